// Round 22
// baseline (94.558 us; speedup 1.0000x reference)
//
#include <hip/hip_runtime.h>
#include <math.h>

#define B_ 4
#define C_ 64
#define D_ 32
#define H_ 64
#define W_ 64
#define S_ (D_*H_*W_)      // 131072 spatial per (b,c)
#define S4_ (S_/4)         // 32768
#define HW_ (H_*W_)        // 4096

typedef float floatx4 __attribute__((ext_vector_type(4)));

// ---------------- Kernel 1: channel-wise max & mean -> xc[B][2][D][H][W] ----
__global__ __launch_bounds__(256) void reduce_kernel(const float* __restrict__ x,
                                                     float* __restrict__ xc) {
    int i  = blockIdx.x * 256 + threadIdx.x;          // float4 index over B*S/4
    int b  = i >> 15;                                  // i / S4_
    int s4 = i & (S4_ - 1);
    const float4* x4 = reinterpret_cast<const float4*>(x) + (size_t)b * C_ * S4_ + s4;
    float4 v = x4[0];
    float mx0 = v.x, mx1 = v.y, mx2 = v.z, mx3 = v.w;
    float sm0 = v.x, sm1 = v.y, sm2 = v.z, sm3 = v.w;
    #pragma unroll 8
    for (int c = 1; c < C_; ++c) {
        float4 t = x4[(size_t)c * S4_];
        mx0 = fmaxf(mx0, t.x); sm0 += t.x;
        mx1 = fmaxf(mx1, t.y); sm1 += t.y;
        mx2 = fmaxf(mx2, t.z); sm2 += t.z;
        mx3 = fmaxf(mx3, t.w); sm3 += t.w;
    }
    float4* o = reinterpret_cast<float4*>(xc);
    float4 a; a.x = mx0; a.y = mx1; a.z = mx2; a.w = mx3;
    o[((size_t)b * 2 + 0) * S4_ + s4] = a;
    const float inv = 1.0f / 64.0f;
    float4 m; m.x = sm0 * inv; m.y = sm1 * inv; m.z = sm2 * inv; m.w = sm3 * inv;
    o[((size_t)b * 2 + 1) * S4_ + s4] = m;
}

// ---------- Kernel 2: conv3d(2->1,k7,p3) + sigmoid -> scale[B][D][H][W] -----
// r18's proven conv structure without the gate stream: 512 blocks x 256 thr,
// 63KB both-channel f32 halo (2 blocks/CU), scalar-loaded weights, conv by
// 128 threads x 2 H-outputs with row-sharing; conv threads store their two
// sigmoid float4s directly to scale.
#define ZT 8
#define YT 14
#define XS 72
#define PLANE (YT*XS)       // 1008
#define CHSZ (ZT*PLANE)     // 8064 floats per channel
#define HALO_N (2*ZT*YT*70) // 15680 logical fill elements

__global__ __launch_bounds__(256, 2) void conv_scale_kernel(const float* __restrict__ xc,
                                                            const float* __restrict__ cw,
                                                            const float* __restrict__ cb,
                                                            float* __restrict__ scale) {
    __shared__ __align__(16) float tile[2 * CHSZ];   // 63 KB -> 2 blocks/CU

    const int tid = threadIdx.x;
    const int b  = blockIdx.z >> 4;            // 16 d-slabs of 2 planes
    const int d0 = (blockIdx.z & 15) * 2;
    const int h0 = blockIdx.y * 8;

    // halo fill, register-staged: 8 independent loads in flight per thread
    for (int base = tid; base < HALO_N; base += 256 * 8) {
        float sv[8];
        int   sa[8];
        #pragma unroll
        for (int k = 0; k < 8; ++k) {
            int idx = base + k * 256;
            sv[k] = 0.f;
            sa[k] = -1;
            if (idx < HALO_N) {
                int ch = idx / 7840;            // ZT*YT*70
                int r  = idx - ch * 7840;
                int z  = r / 980;               // YT*70
                int r2 = r - z * 980;
                int y  = r2 / 70;
                int xw = r2 - y * 70;
                sa[k] = ch * CHSZ + z * PLANE + y * XS + xw;
                int gd = d0 + z - 3, gh = h0 + y - 3, gw = xw - 3;
                if ((unsigned)gd < (unsigned)D_ && (unsigned)gh < (unsigned)H_ &&
                    (unsigned)gw < (unsigned)W_)
                    sv[k] = xc[(size_t)(b * 2 + ch) * S_ + gd * HW_ + gh * W_ + gw];
            }
        }
        #pragma unroll
        for (int k = 0; k < 8; ++k)
            if (sa[k] >= 0) tile[sa[k]] = sv[k];
    }
    __syncthreads();   // halo visible

    // ---- conv: 128 threads, 2 H-outputs each, row-sharing ----
    if (tid < 128) {
        const int cw4 = tid & 15;           // w = 4*cw4
        const int chg = (tid >> 4) & 3;     // H pair = h0 + 2*chg (+0,+1)
        const int cdd = (tid >> 6) & 1;     // d = d0 + cdd
        float acc0[4] = {0.f, 0.f, 0.f, 0.f};   // H = 2*chg
        float acc1[4] = {0.f, 0.f, 0.f, 0.f};   // H = 2*chg + 1
        for (int ch = 0; ch < 2; ++ch) {
            const float* tch = &tile[ch * CHSZ + cdd * PLANE + cw4 * 4];
            const float* wch = cw + ch * 343;
            for (int kz = 0; kz < 7; ++kz) {
                const float* trow = tch + kz * PLANE + (chg * 2) * XS;
                const float* wkz  = wch + kz * 49;
                float wp[7];
                #pragma unroll
                for (int r = 0; r < 8; ++r) {
                    const float* rp = trow + r * XS;
                    float4 f0 = *reinterpret_cast<const float4*>(rp);
                    float4 f1 = *reinterpret_cast<const float4*>(rp + 4);
                    float2 f2 = *reinterpret_cast<const float2*>(rp + 8);
                    float win[10] = {f0.x, f0.y, f0.z, f0.w,
                                     f1.x, f1.y, f1.z, f1.w, f2.x, f2.y};
                    if (r >= 1) {                  // output1: ky = r-1 (slid)
                        #pragma unroll
                        for (int kw = 0; kw < 7; ++kw) {
                            acc1[0] = fmaf(win[kw + 0], wp[kw], acc1[0]);
                            acc1[1] = fmaf(win[kw + 1], wp[kw], acc1[1]);
                            acc1[2] = fmaf(win[kw + 2], wp[kw], acc1[2]);
                            acc1[3] = fmaf(win[kw + 3], wp[kw], acc1[3]);
                        }
                    }
                    if (r < 7) {                   // output0: ky = r
                        const float* wr = wkz + r * 7;   // uniform -> s_load
                        float wc[7];
                        #pragma unroll
                        for (int k = 0; k < 7; ++k) wc[k] = wr[k];
                        #pragma unroll
                        for (int kw = 0; kw < 7; ++kw) {
                            acc0[0] = fmaf(win[kw + 0], wc[kw], acc0[0]);
                            acc0[1] = fmaf(win[kw + 1], wc[kw], acc0[1]);
                            acc0[2] = fmaf(win[kw + 2], wc[kw], acc0[2]);
                            acc0[3] = fmaf(win[kw + 3], wc[kw], acc0[3]);
                        }
                        #pragma unroll
                        for (int k = 0; k < 7; ++k) wp[k] = wc[k];
                    }
                }
            }
        }
        const float bias = cb[0];
        floatx4 s0, s1;
        s0.x = 1.0f / (1.0f + __expf(-(acc0[0] + bias)));
        s0.y = 1.0f / (1.0f + __expf(-(acc0[1] + bias)));
        s0.z = 1.0f / (1.0f + __expf(-(acc0[2] + bias)));
        s0.w = 1.0f / (1.0f + __expf(-(acc0[3] + bias)));
        s1.x = 1.0f / (1.0f + __expf(-(acc1[0] + bias)));
        s1.y = 1.0f / (1.0f + __expf(-(acc1[1] + bias)));
        s1.z = 1.0f / (1.0f + __expf(-(acc1[2] + bias)));
        s1.w = 1.0f / (1.0f + __expf(-(acc1[3] + bias)));
        float* sp = &scale[(size_t)b * S_ + (size_t)(d0 + cdd) * HW_ +
                           (size_t)(h0 + chg * 2) * W_ + cw4 * 4];
        *reinterpret_cast<floatx4*>(sp)      = s0;
        *reinterpret_cast<floatx4*>(sp + W_) = s1;
    }
}

// ---------------- Kernel 3: out = x * scale, full-occupancy streamer --------
// 2048 blocks x 256 thr (~32 waves/CU). Thread: one (b,s4) position x 16
// channels; one scale load per thread; 8-deep load batches, regular stores.
__global__ __launch_bounds__(256) void gate_kernel(const float* __restrict__ x,
                                                   const float* __restrict__ scale,
                                                   float* __restrict__ out) {
    int t = blockIdx.x * 256 + threadIdx.x;      // 524288 threads
    int cchunk = t >> 17;                        // 0..3 -> channels 16*cchunk..
    int pos = t & 131071;                        // (b,s4)
    int b  = pos >> 15;
    int s4 = pos & (S4_ - 1);
    const floatx4* xp = reinterpret_cast<const floatx4*>(x) + (size_t)b * C_ * S4_ + s4;
    floatx4* op = reinterpret_cast<floatx4*>(out) + (size_t)b * C_ * S4_ + s4;
    const floatx4 sc = reinterpret_cast<const floatx4*>(scale)[(size_t)b * S4_ + s4];
    const int c0 = cchunk * 16;
    #pragma unroll
    for (int half = 0; half < 2; ++half) {
        const int cb_ = c0 + half * 8;
        floatx4 v[8];
        #pragma unroll
        for (int k = 0; k < 8; ++k)
            v[k] = xp[(size_t)(cb_ + k) * S4_];
        #pragma unroll
        for (int k = 0; k < 8; ++k)
            op[(size_t)(cb_ + k) * S4_] = v[k] * sc;
    }
}

extern "C" void kernel_launch(void* const* d_in, const int* in_sizes, int n_in,
                              void* d_out, int out_size, void* d_ws, size_t ws_size,
                              hipStream_t stream) {
    const float* x  = (const float*)d_in[0];
    const float* cw = (const float*)d_in[1];   // [1][2][7][7][7]
    const float* cb = (const float*)d_in[2];   // [1]
    float* out   = (float*)d_out;
    float* xc    = (float*)d_ws;                       // B*2*S floats (4 MiB)
    float* scale = xc + (size_t)B_ * 2 * S_;           // B*S floats (2 MiB)

    reduce_kernel<<<dim3((B_ * S4_) / 256), dim3(256), 0, stream>>>(x, xc);
    conv_scale_kernel<<<dim3(1, H_ / 8, B_ * (D_ / 2)), dim3(256), 0, stream>>>(
        xc, cw, cb, scale);
    gate_kernel<<<dim3(2048), dim3(256), 0, stream>>>(x, scale, out);
}

// Round 23
// 80.932 us; speedup vs baseline: 1.1684x; 1.1684x over previous
//
#include <hip/hip_runtime.h>
#include <math.h>

#define B_ 4
#define C_ 64
#define D_ 32
#define H_ 64
#define W_ 64
#define S_ (D_*H_*W_)      // 131072 spatial per (b,c)
#define S4_ (S_/4)         // 32768
#define HW_ (H_*W_)        // 4096

typedef float floatx4 __attribute__((ext_vector_type(4)));

// ---------------- Kernel 1: channel-wise max & mean -> xc[B][2][D][H][W] ----
__global__ __launch_bounds__(256) void reduce_kernel(const float* __restrict__ x,
                                                     float* __restrict__ xc) {
    int i  = blockIdx.x * 256 + threadIdx.x;          // float4 index over B*S/4
    int b  = i >> 15;                                  // i / S4_
    int s4 = i & (S4_ - 1);
    const float4* x4 = reinterpret_cast<const float4*>(x) + (size_t)b * C_ * S4_ + s4;
    float4 v = x4[0];
    float mx0 = v.x, mx1 = v.y, mx2 = v.z, mx3 = v.w;
    float sm0 = v.x, sm1 = v.y, sm2 = v.z, sm3 = v.w;
    #pragma unroll 8
    for (int c = 1; c < C_; ++c) {
        float4 t = x4[(size_t)c * S4_];
        mx0 = fmaxf(mx0, t.x); sm0 += t.x;
        mx1 = fmaxf(mx1, t.y); sm1 += t.y;
        mx2 = fmaxf(mx2, t.z); sm2 += t.z;
        mx3 = fmaxf(mx3, t.w); sm3 += t.w;
    }
    float4* o = reinterpret_cast<float4*>(xc);
    float4 a; a.x = mx0; a.y = mx1; a.z = mx2; a.w = mx3;
    o[((size_t)b * 2 + 0) * S4_ + s4] = a;
    const float inv = 1.0f / 64.0f;
    float4 m; m.x = sm0 * inv; m.y = sm1 * inv; m.z = sm2 * inv; m.w = sm3 * inv;
    o[((size_t)b * 2 + 1) * S4_ + s4] = m;
}

// ------- Kernel 2 (fused): conv3d(2->1,k7,p3) + sigmoid + out = x*scale -----
// EXACT r19 structure (best measured: 82.5us) + idle-wave prefetch: during
// the conv phase (tid<128 computing), waves 4-7 prefetch gate chunks 2-3
// (v1[16], live only on their path) so 16MB more of the x-read streams
// under the serial conv window.
#define ZT 8
#define YT 14
#define XS 72
#define PLANE (YT*XS)       // 1008
#define CHSZ (ZT*PLANE)     // 8064 floats per channel
#define HALO_N (2*ZT*YT*70) // 15680 logical fill elements

__global__ __launch_bounds__(256, 2) void conv_gate_kernel(const float* __restrict__ xc,
                                                           const float* __restrict__ x,
                                                           const float* __restrict__ cw,
                                                           const float* __restrict__ cb,
                                                           float* __restrict__ out) {
    __shared__ __align__(16) float tile[2 * CHSZ];   // 63 KB -> 2 blocks/CU

    const int tid = threadIdx.x;
    const int b  = blockIdx.z >> 4;            // 16 d-slabs of 2 planes
    const int d0 = (blockIdx.z & 15) * 2;
    const int h0 = blockIdx.y * 8;

    // stream mapping (all 256 threads): one f4 position
    const int sw4 = tid & 15;
    const int shh = (tid >> 4) & 7;
    const int sdd = tid >> 7;

    // halo fill, register-staged: 8 independent loads in flight per thread
    for (int base = tid; base < HALO_N; base += 256 * 8) {
        float sv[8];
        int   sa[8];
        #pragma unroll
        for (int k = 0; k < 8; ++k) {
            int idx = base + k * 256;
            sv[k] = 0.f;
            sa[k] = -1;
            if (idx < HALO_N) {
                int ch = idx / 7840;            // ZT*YT*70
                int r  = idx - ch * 7840;
                int z  = r / 980;               // YT*70
                int r2 = r - z * 980;
                int y  = r2 / 70;
                int xw = r2 - y * 70;
                sa[k] = ch * CHSZ + z * PLANE + y * XS + xw;
                int gd = d0 + z - 3, gh = h0 + y - 3, gw = xw - 3;
                if ((unsigned)gd < (unsigned)D_ && (unsigned)gh < (unsigned)H_ &&
                    (unsigned)gw < (unsigned)W_)
                    sv[k] = xc[(size_t)(b * 2 + ch) * S_ + gd * HW_ + gh * W_ + gw];
            }
        }
        #pragma unroll
        for (int k = 0; k < 8; ++k)
            if (sa[k] >= 0) tile[sa[k]] = sv[k];
    }

    // gate preload of chunks 0-1 (16 channels): in flight through fill+conv
    const size_t sp = (size_t)(d0 + sdd) * HW_ + (size_t)(h0 + shh) * W_ + sw4 * 4;
    const float* xp = x + (size_t)b * C_ * S_ + sp;
    float* op = out + (size_t)b * C_ * S_ + sp;
    floatx4 v0[16];
    #pragma unroll
    for (int k = 0; k < 16; ++k)
        v0[k] = *reinterpret_cast<const floatx4*>(xp + (size_t)k * S_);

    __syncthreads();   // halo visible

    // ---- conv phase (tid<128) / idle-wave prefetch (tid>=128) ----
    floatx4 s0, s1;
    floatx4 v1[16];                      // live only on the tid>=128 path
    const int cw4 = tid & 15;            // w = 4*cw4
    const int chg = (tid >> 4) & 3;      // H pair = h0 + 2*chg (+0,+1)
    const int cdd = (tid >> 6) & 1;      // d = d0 + cdd
    if (tid < 128) {
        float acc0[4] = {0.f, 0.f, 0.f, 0.f};   // H = 2*chg
        float acc1[4] = {0.f, 0.f, 0.f, 0.f};   // H = 2*chg + 1
        for (int ch = 0; ch < 2; ++ch) {
            const float* tch = &tile[ch * CHSZ + cdd * PLANE + cw4 * 4];
            const float* wch = cw + ch * 343;
            for (int kz = 0; kz < 7; ++kz) {
                const float* trow = tch + kz * PLANE + (chg * 2) * XS;
                const float* wkz  = wch + kz * 49;
                float wp[7];
                #pragma unroll
                for (int r = 0; r < 8; ++r) {
                    const float* rp = trow + r * XS;
                    float4 f0 = *reinterpret_cast<const float4*>(rp);
                    float4 f1 = *reinterpret_cast<const float4*>(rp + 4);
                    float2 f2 = *reinterpret_cast<const float2*>(rp + 8);
                    float win[10] = {f0.x, f0.y, f0.z, f0.w,
                                     f1.x, f1.y, f1.z, f1.w, f2.x, f2.y};
                    if (r >= 1) {                  // output1: ky = r-1 (slid)
                        #pragma unroll
                        for (int kw = 0; kw < 7; ++kw) {
                            acc1[0] = fmaf(win[kw + 0], wp[kw], acc1[0]);
                            acc1[1] = fmaf(win[kw + 1], wp[kw], acc1[1]);
                            acc1[2] = fmaf(win[kw + 2], wp[kw], acc1[2]);
                            acc1[3] = fmaf(win[kw + 3], wp[kw], acc1[3]);
                        }
                    }
                    if (r < 7) {                   // output0: ky = r
                        const float* wr = wkz + r * 7;   // uniform -> s_load
                        float wc[7];
                        #pragma unroll
                        for (int k = 0; k < 7; ++k) wc[k] = wr[k];
                        #pragma unroll
                        for (int kw = 0; kw < 7; ++kw) {
                            acc0[0] = fmaf(win[kw + 0], wc[kw], acc0[0]);
                            acc0[1] = fmaf(win[kw + 1], wc[kw], acc0[1]);
                            acc0[2] = fmaf(win[kw + 2], wc[kw], acc0[2]);
                            acc0[3] = fmaf(win[kw + 3], wc[kw], acc0[3]);
                        }
                        #pragma unroll
                        for (int k = 0; k < 7; ++k) wp[k] = wc[k];
                    }
                }
            }
        }
        const float bias = cb[0];
        s0.x = 1.0f / (1.0f + __expf(-(acc0[0] + bias)));
        s0.y = 1.0f / (1.0f + __expf(-(acc0[1] + bias)));
        s0.z = 1.0f / (1.0f + __expf(-(acc0[2] + bias)));
        s0.w = 1.0f / (1.0f + __expf(-(acc0[3] + bias)));
        s1.x = 1.0f / (1.0f + __expf(-(acc1[0] + bias)));
        s1.y = 1.0f / (1.0f + __expf(-(acc1[1] + bias)));
        s1.z = 1.0f / (1.0f + __expf(-(acc1[2] + bias)));
        s1.w = 1.0f / (1.0f + __expf(-(acc1[3] + bias)));
    } else {
        // idle waves: prefetch chunks 2-3 for their own positions
        #pragma unroll
        for (int k = 0; k < 16; ++k)
            v1[k] = *reinterpret_cast<const floatx4*>(xp + (size_t)(16 + k) * S_);
    }
    __syncthreads();   // all conv reads of tile done

    // ---- scale handoff: overlay float4[256] on dead halo ----
    floatx4* scl = reinterpret_cast<floatx4*>(tile);
    if (tid < 128) {
        scl[(cdd * 8 + chg * 2 + 0) * 16 + cw4] = s0;
        scl[(cdd * 8 + chg * 2 + 1) * 16 + cw4] = s1;
    }
    __syncthreads();

    // ---- gating stream ----
    const floatx4 sc = scl[(sdd * 8 + shh) * 16 + sw4];
    #pragma unroll
    for (int k = 0; k < 16; ++k)
        *reinterpret_cast<floatx4*>(op + (size_t)k * S_) = v0[k] * sc;
    if (tid < 128) {
        for (int c = 16; c < C_; c += 8) {
            floatx4 v[8];
            #pragma unroll
            for (int k = 0; k < 8; ++k)
                v[k] = *reinterpret_cast<const floatx4*>(xp + (size_t)(c + k) * S_);
            #pragma unroll
            for (int k = 0; k < 8; ++k)
                *reinterpret_cast<floatx4*>(op + (size_t)(c + k) * S_) = v[k] * sc;
        }
    } else {
        #pragma unroll
        for (int k = 0; k < 16; ++k)
            *reinterpret_cast<floatx4*>(op + (size_t)(16 + k) * S_) = v1[k] * sc;
        for (int c = 32; c < C_; c += 8) {
            floatx4 v[8];
            #pragma unroll
            for (int k = 0; k < 8; ++k)
                v[k] = *reinterpret_cast<const floatx4*>(xp + (size_t)(c + k) * S_);
            #pragma unroll
            for (int k = 0; k < 8; ++k)
                *reinterpret_cast<floatx4*>(op + (size_t)(c + k) * S_) = v[k] * sc;
        }
    }
}

extern "C" void kernel_launch(void* const* d_in, const int* in_sizes, int n_in,
                              void* d_out, int out_size, void* d_ws, size_t ws_size,
                              hipStream_t stream) {
    const float* x  = (const float*)d_in[0];
    const float* cw = (const float*)d_in[1];   // [1][2][7][7][7]
    const float* cb = (const float*)d_in[2];   // [1]
    float* out = (float*)d_out;
    float* xc  = (float*)d_ws;                 // B*2*S floats (4 MiB)

    reduce_kernel<<<dim3((B_ * S4_) / 256), dim3(256), 0, stream>>>(x, xc);
    conv_gate_kernel<<<dim3(1, H_ / 8, B_ * (D_ / 2)), dim3(256), 0, stream>>>(
        xc, x, cw, cb, out);
}

// Round 24
// 80.825 us; speedup vs baseline: 1.1699x; 1.0013x over previous
//
#include <hip/hip_runtime.h>
#include <math.h>

#define B_ 4
#define C_ 64
#define D_ 32
#define H_ 64
#define W_ 64
#define S_ (D_*H_*W_)      // 131072 spatial per (b,c)
#define S4_ (S_/4)         // 32768
#define HW_ (H_*W_)        // 4096

typedef float floatx4 __attribute__((ext_vector_type(4)));

// ---------------- Kernel 1: channel-wise max & mean -> xc[B][2][D][H][W] ----
__global__ __launch_bounds__(256) void reduce_kernel(const float* __restrict__ x,
                                                     float* __restrict__ xc) {
    int i  = blockIdx.x * 256 + threadIdx.x;          // float4 index over B*S/4
    int b  = i >> 15;                                  // i / S4_
    int s4 = i & (S4_ - 1);
    const float4* x4 = reinterpret_cast<const float4*>(x) + (size_t)b * C_ * S4_ + s4;
    float4 v = x4[0];
    float mx0 = v.x, mx1 = v.y, mx2 = v.z, mx3 = v.w;
    float sm0 = v.x, sm1 = v.y, sm2 = v.z, sm3 = v.w;
    #pragma unroll 8
    for (int c = 1; c < C_; ++c) {
        float4 t = x4[(size_t)c * S4_];
        mx0 = fmaxf(mx0, t.x); sm0 += t.x;
        mx1 = fmaxf(mx1, t.y); sm1 += t.y;
        mx2 = fmaxf(mx2, t.z); sm2 += t.z;
        mx3 = fmaxf(mx3, t.w); sm3 += t.w;
    }
    float4* o = reinterpret_cast<float4*>(xc);
    float4 a; a.x = mx0; a.y = mx1; a.z = mx2; a.w = mx3;
    o[((size_t)b * 2 + 0) * S4_ + s4] = a;
    const float inv = 1.0f / 64.0f;
    float4 m; m.x = sm0 * inv; m.y = sm1 * inv; m.z = sm2 * inv; m.w = sm3 * inv;
    o[((size_t)b * 2 + 1) * S4_ + s4] = m;
}

// ------- Kernel 2 (fused): conv3d(2->1,k7,p3) + sigmoid + out = x*scale -----
// r23 structure (best: 80.9us) with the idle-wave prefetch deepened to
// v1[32] (channels 16-47): 32MB more of the x-read issued under the serial
// fill+conv window. Idle-path VGPR ~225 < 256 -> still 2 blocks/CU.
#define ZT 8
#define YT 14
#define XS 72
#define PLANE (YT*XS)       // 1008
#define CHSZ (ZT*PLANE)     // 8064 floats per channel
#define HALO_N (2*ZT*YT*70) // 15680 logical fill elements

__global__ __launch_bounds__(256, 2) void conv_gate_kernel(const float* __restrict__ xc,
                                                           const float* __restrict__ x,
                                                           const float* __restrict__ cw,
                                                           const float* __restrict__ cb,
                                                           float* __restrict__ out) {
    __shared__ __align__(16) float tile[2 * CHSZ];   // 63 KB -> 2 blocks/CU

    const int tid = threadIdx.x;
    const int b  = blockIdx.z >> 4;            // 16 d-slabs of 2 planes
    const int d0 = (blockIdx.z & 15) * 2;
    const int h0 = blockIdx.y * 8;

    // stream mapping (all 256 threads): one f4 position
    const int sw4 = tid & 15;
    const int shh = (tid >> 4) & 7;
    const int sdd = tid >> 7;

    // halo fill, register-staged: 8 independent loads in flight per thread
    for (int base = tid; base < HALO_N; base += 256 * 8) {
        float sv[8];
        int   sa[8];
        #pragma unroll
        for (int k = 0; k < 8; ++k) {
            int idx = base + k * 256;
            sv[k] = 0.f;
            sa[k] = -1;
            if (idx < HALO_N) {
                int ch = idx / 7840;            // ZT*YT*70
                int r  = idx - ch * 7840;
                int z  = r / 980;               // YT*70
                int r2 = r - z * 980;
                int y  = r2 / 70;
                int xw = r2 - y * 70;
                sa[k] = ch * CHSZ + z * PLANE + y * XS + xw;
                int gd = d0 + z - 3, gh = h0 + y - 3, gw = xw - 3;
                if ((unsigned)gd < (unsigned)D_ && (unsigned)gh < (unsigned)H_ &&
                    (unsigned)gw < (unsigned)W_)
                    sv[k] = xc[(size_t)(b * 2 + ch) * S_ + gd * HW_ + gh * W_ + gw];
            }
        }
        #pragma unroll
        for (int k = 0; k < 8; ++k)
            if (sa[k] >= 0) tile[sa[k]] = sv[k];
    }

    // gate preload of chunks 0-1 (16 channels): in flight through fill+conv
    const size_t sp = (size_t)(d0 + sdd) * HW_ + (size_t)(h0 + shh) * W_ + sw4 * 4;
    const float* xp = x + (size_t)b * C_ * S_ + sp;
    float* op = out + (size_t)b * C_ * S_ + sp;
    floatx4 v0[16];
    #pragma unroll
    for (int k = 0; k < 16; ++k)
        v0[k] = *reinterpret_cast<const floatx4*>(xp + (size_t)k * S_);

    __syncthreads();   // halo visible

    // ---- conv phase (tid<128) / idle-wave prefetch (tid>=128) ----
    floatx4 s0, s1;
    floatx4 v1[32];                      // live only on the tid>=128 path
    const int cw4 = tid & 15;            // w = 4*cw4
    const int chg = (tid >> 4) & 3;      // H pair = h0 + 2*chg (+0,+1)
    const int cdd = (tid >> 6) & 1;      // d = d0 + cdd
    if (tid < 128) {
        float acc0[4] = {0.f, 0.f, 0.f, 0.f};   // H = 2*chg
        float acc1[4] = {0.f, 0.f, 0.f, 0.f};   // H = 2*chg + 1
        for (int ch = 0; ch < 2; ++ch) {
            const float* tch = &tile[ch * CHSZ + cdd * PLANE + cw4 * 4];
            const float* wch = cw + ch * 343;
            for (int kz = 0; kz < 7; ++kz) {
                const float* trow = tch + kz * PLANE + (chg * 2) * XS;
                const float* wkz  = wch + kz * 49;
                float wp[7];
                #pragma unroll
                for (int r = 0; r < 8; ++r) {
                    const float* rp = trow + r * XS;
                    float4 f0 = *reinterpret_cast<const float4*>(rp);
                    float4 f1 = *reinterpret_cast<const float4*>(rp + 4);
                    float2 f2 = *reinterpret_cast<const float2*>(rp + 8);
                    float win[10] = {f0.x, f0.y, f0.z, f0.w,
                                     f1.x, f1.y, f1.z, f1.w, f2.x, f2.y};
                    if (r >= 1) {                  // output1: ky = r-1 (slid)
                        #pragma unroll
                        for (int kw = 0; kw < 7; ++kw) {
                            acc1[0] = fmaf(win[kw + 0], wp[kw], acc1[0]);
                            acc1[1] = fmaf(win[kw + 1], wp[kw], acc1[1]);
                            acc1[2] = fmaf(win[kw + 2], wp[kw], acc1[2]);
                            acc1[3] = fmaf(win[kw + 3], wp[kw], acc1[3]);
                        }
                    }
                    if (r < 7) {                   // output0: ky = r
                        const float* wr = wkz + r * 7;   // uniform -> s_load
                        float wc[7];
                        #pragma unroll
                        for (int k = 0; k < 7; ++k) wc[k] = wr[k];
                        #pragma unroll
                        for (int kw = 0; kw < 7; ++kw) {
                            acc0[0] = fmaf(win[kw + 0], wc[kw], acc0[0]);
                            acc0[1] = fmaf(win[kw + 1], wc[kw], acc0[1]);
                            acc0[2] = fmaf(win[kw + 2], wc[kw], acc0[2]);
                            acc0[3] = fmaf(win[kw + 3], wc[kw], acc0[3]);
                        }
                        #pragma unroll
                        for (int k = 0; k < 7; ++k) wp[k] = wc[k];
                    }
                }
            }
        }
        const float bias = cb[0];
        s0.x = 1.0f / (1.0f + __expf(-(acc0[0] + bias)));
        s0.y = 1.0f / (1.0f + __expf(-(acc0[1] + bias)));
        s0.z = 1.0f / (1.0f + __expf(-(acc0[2] + bias)));
        s0.w = 1.0f / (1.0f + __expf(-(acc0[3] + bias)));
        s1.x = 1.0f / (1.0f + __expf(-(acc1[0] + bias)));
        s1.y = 1.0f / (1.0f + __expf(-(acc1[1] + bias)));
        s1.z = 1.0f / (1.0f + __expf(-(acc1[2] + bias)));
        s1.w = 1.0f / (1.0f + __expf(-(acc1[3] + bias)));
    } else {
        // idle waves: prefetch channels 16-47 for their own positions
        #pragma unroll
        for (int k = 0; k < 32; ++k)
            v1[k] = *reinterpret_cast<const floatx4*>(xp + (size_t)(16 + k) * S_);
    }
    __syncthreads();   // all conv reads of tile done

    // ---- scale handoff: overlay float4[256] on dead halo ----
    floatx4* scl = reinterpret_cast<floatx4*>(tile);
    if (tid < 128) {
        scl[(cdd * 8 + chg * 2 + 0) * 16 + cw4] = s0;
        scl[(cdd * 8 + chg * 2 + 1) * 16 + cw4] = s1;
    }
    __syncthreads();

    // ---- gating stream ----
    const floatx4 sc = scl[(sdd * 8 + shh) * 16 + sw4];
    #pragma unroll
    for (int k = 0; k < 16; ++k)
        *reinterpret_cast<floatx4*>(op + (size_t)k * S_) = v0[k] * sc;
    if (tid < 128) {
        for (int c = 16; c < C_; c += 8) {
            floatx4 v[8];
            #pragma unroll
            for (int k = 0; k < 8; ++k)
                v[k] = *reinterpret_cast<const floatx4*>(xp + (size_t)(c + k) * S_);
            #pragma unroll
            for (int k = 0; k < 8; ++k)
                *reinterpret_cast<floatx4*>(op + (size_t)(c + k) * S_) = v[k] * sc;
        }
    } else {
        #pragma unroll
        for (int k = 0; k < 32; ++k)
            *reinterpret_cast<floatx4*>(op + (size_t)(16 + k) * S_) = v1[k] * sc;
        for (int c = 48; c < C_; c += 8) {
            floatx4 v[8];
            #pragma unroll
            for (int k = 0; k < 8; ++k)
                v[k] = *reinterpret_cast<const floatx4*>(xp + (size_t)(c + k) * S_);
            #pragma unroll
            for (int k = 0; k < 8; ++k)
                *reinterpret_cast<floatx4*>(op + (size_t)(c + k) * S_) = v[k] * sc;
        }
    }
}

extern "C" void kernel_launch(void* const* d_in, const int* in_sizes, int n_in,
                              void* d_out, int out_size, void* d_ws, size_t ws_size,
                              hipStream_t stream) {
    const float* x  = (const float*)d_in[0];
    const float* cw = (const float*)d_in[1];   // [1][2][7][7][7]
    const float* cb = (const float*)d_in[2];   // [1]
    float* out = (float*)d_out;
    float* xc  = (float*)d_ws;                 // B*2*S floats (4 MiB)

    reduce_kernel<<<dim3((B_ * S4_) / 256), dim3(256), 0, stream>>>(x, xc);
    conv_gate_kernel<<<dim3(1, H_ / 8, B_ * (D_ / 2)), dim3(256), 0, stream>>>(
        xc, x, cw, cb, out);
}